// Round 3
// baseline (33.109 us; speedup 1.0000x reference)
//
#include <hip/hip_runtime.h>
#include <stdint.h>

typedef float    f32x4 __attribute__((ext_vector_type(4)));
typedef uint32_t u32x4 __attribute__((ext_vector_type(4)));

// ws layout (bytes):
//  [0, 65536)       fp8 codebook, t-grouped lane order:
//                   chunk c = t*64 + l (t=code tile, l=lane): 16B at c*16 =
//                   { fp8(1024*e[16t+(l&15)][(l>>4)*8 .. +8)),
//                     fp8(1024*e[16t+(l&15)][32+(l>>4)*8 .. +8)) }
//  [65536, 69632)   e2 fp32[1024] (unscaled, exact)
#define WS_E2   65536

// LDS: mirrors ws [0,69632) linearly, + idx + loss scratch
#define SM_E2   65536
#define SM_IDX  69632   // 8 waves * 16 int = 512B
#define SM_LOSS 70144   // 8 floats
#define SM_SZ   70176

__device__ __forceinline__ uint32_t pk4(float a, float b, float c, float d) {
  int v = 0;
  v = __builtin_amdgcn_cvt_pk_fp8_f32(a, b, v, false);
  v = __builtin_amdgcn_cvt_pk_fp8_f32(c, d, v, true);
  return (uint32_t)v;
}

__device__ __forceinline__ float d4(f32x4 v) {
  return v[0]*v[0] + v[1]*v[1] + v[2]*v[2] + v[3]*v[3];
}

// 8 blocks x 512: thread -> one 16B fp8 chunk + one e2 quarter-row (coalesced)
__global__ __launch_bounds__(512) void prep_kernel(const float* __restrict__ cb,
                                                   uint8_t* __restrict__ ws) {
  const int tid = threadIdx.x;
  // fp8 chunk c: write-sequential layout
  const int c = blockIdx.x * 512 + tid;          // 0..4095
  const int t = c >> 6, l = c & 63, lr = l & 15, lg = l >> 4;
  {
    const float* row = cb + (size_t)(t * 16 + lr) * 64 + lg * 8;
    f32x4 a0 = *(const f32x4*)row;
    f32x4 a1 = *(const f32x4*)(row + 4);
    f32x4 b0 = *(const f32x4*)(row + 32);
    f32x4 b1 = *(const f32x4*)(row + 36);
    u32x4 o;
    o[0] = pk4(1024.f*a0[0], 1024.f*a0[1], 1024.f*a0[2], 1024.f*a0[3]);
    o[1] = pk4(1024.f*a1[0], 1024.f*a1[1], 1024.f*a1[2], 1024.f*a1[3]);
    o[2] = pk4(1024.f*b0[0], 1024.f*b0[1], 1024.f*b0[2], 1024.f*b0[3]);
    o[3] = pk4(1024.f*b1[0], 1024.f*b1[1], 1024.f*b1[2], 1024.f*b1[3]);
    *(u32x4*)(ws + (size_t)c * 16) = o;
  }
  // e2: 4 lanes per row, 64B coalesced per lane
  {
    const int r = blockIdx.x * 128 + (tid >> 2), q = tid & 3;
    const float* rp = cb + (size_t)r * 64 + q * 16;
    f32x4 v0 = *(const f32x4*)rp;
    f32x4 v1 = *(const f32x4*)(rp + 4);
    f32x4 v2 = *(const f32x4*)(rp + 8);
    f32x4 v3 = *(const f32x4*)(rp + 12);
    float s = d4(v0) + d4(v1) + d4(v2) + d4(v3);
    s += __shfl_xor(s, 1, 64);
    s += __shfl_xor(s, 2, 64);
    if (q == 0) *(float*)(ws + WS_E2 + (size_t)r * 4) = s;
  }
}

__global__ __launch_bounds__(512, 4) void vq_main(const float* __restrict__ x,
                                                  const float* __restrict__ cb,
                                                  float* __restrict__ out,
                                                  const uint8_t* __restrict__ ws,
                                                  float* __restrict__ loss) {
  __shared__ __align__(16) uint8_t smem[SM_SZ];
  const int tid = threadIdx.x, lane = tid & 63, w = tid >> 6;
  const int lr = lane & 15, lg = lane >> 4;
  const int rowbase = blockIdx.x * 256 + w * 32;

  // ---- issue async staging first: fp8 codebook (64KB) + e2 (4KB) ----
  {
    const uint8_t* gsrc = ws + (size_t)w * 8192 + (size_t)lane * 16;
    uint8_t* ldst = smem + w * 8192;
#pragma unroll
    for (int i = 0; i < 8; ++i)
      __builtin_amdgcn_global_load_lds(
          (const __attribute__((address_space(1))) uint32_t*)(gsrc + i * 1024),
          (__attribute__((address_space(3))) uint32_t*)(ldst + i * 1024), 16, 0, 0);
    if (w < 4)
      __builtin_amdgcn_global_load_lds(
          (const __attribute__((address_space(1))) uint32_t*)(ws + WS_E2 + (size_t)w * 1024 + (size_t)lane * 16),
          (__attribute__((address_space(3))) uint32_t*)(smem + SM_E2 + w * 1024), 16, 0, 0);
  }

  // ---- load x rows (nontemporal), fp32 x^2 partial, pack fp8 A-frags ----
  float x2p = 0.f;
  long afrag[2][2];
#pragma unroll
  for (int rt = 0; rt < 2; ++rt) {
    const float* rp = x + (size_t)(rowbase + rt * 16 + lr) * 64 + lg * 8;
    f32x4 a0 = __builtin_nontemporal_load((const f32x4*)rp);
    f32x4 a1 = __builtin_nontemporal_load((const f32x4*)(rp + 4));
    f32x4 b0 = __builtin_nontemporal_load((const f32x4*)(rp + 32));
    f32x4 b1 = __builtin_nontemporal_load((const f32x4*)(rp + 36));
    x2p += d4(a0) + d4(a1) + d4(b0) + d4(b1);
    uint32_t w0 = pk4(a0[0], a0[1], a0[2], a0[3]);
    uint32_t w1 = pk4(a1[0], a1[1], a1[2], a1[3]);
    uint32_t w2 = pk4(b0[0], b0[1], b0[2], b0[3]);
    uint32_t w3 = pk4(b1[0], b1[1], b1[2], b1[3]);
    afrag[rt][0] = (long)(((uint64_t)w1 << 32) | w0);
    afrag[rt][1] = (long)(((uint64_t)w3 << 32) | w2);
  }
  __syncthreads();

  const float* e2f = (const float*)(smem + SM_E2);
  int* sh_idx = (int*)(smem + SM_IDX) + w * 16;
  float lsum = x2p;

  // ---- two 16-row passes: argmax (MFMA) -> gather+store, store overlaps pass 2 ----
#pragma unroll
  for (int pass = 0; pass < 2; ++pass) {
    float kmax[4];
#pragma unroll
    for (int r = 0; r < 4; ++r) kmax[r] = __builtin_bit_cast(float, 0xFF800000u);

    const uint8_t* bptr = smem + lane * 16;
    uint32_t jcur = (uint32_t)lr;
#pragma unroll 4
    for (int t = 0; t < 64; ++t) {
      u32x4 b = *(const u32x4*)(bptr + t * 1024);
      long bf0 = (long)(((uint64_t)b[1] << 32) | b[0]);
      long bf1 = (long)(((uint64_t)b[3] << 32) | b[2]);
      f32x4 acc = {0.f, 0.f, 0.f, 0.f};
      acc = __builtin_amdgcn_mfma_f32_16x16x32_fp8_fp8(afrag[pass][0], bf0, acc, 0, 0, 0);
      acc = __builtin_amdgcn_mfma_f32_16x16x32_fp8_fp8(afrag[pass][1], bf1, acc, 0, 0, 0);
#pragma unroll
      for (int r = 0; r < 4; ++r) {
        uint32_t key = (__builtin_bit_cast(uint32_t, acc[r]) & 0xFFFFFC00u) | jcur;
        kmax[r] = fmaxf(kmax[r], __builtin_bit_cast(float, key));
      }
      jcur += 16;
    }

    // reduce over the 16 code-slot lanes; loss dot term
#pragma unroll
    for (int r = 0; r < 4; ++r) {
      float v = kmax[r];
#pragma unroll
      for (int m = 1; m < 16; m <<= 1) v = fmaxf(v, __shfl_xor(v, m, 64));
      kmax[r] = v;
      lsum -= __builtin_bit_cast(float, __builtin_bit_cast(uint32_t, v) & 0xFFFFFC00u)
              * (1.0f / 8192.0f);
    }

    // exchange per-row indices (wave-local)
    if (lr == 0) {
#pragma unroll
      for (int r = 0; r < 4; ++r)
        sh_idx[lg * 4 + r] = (int)(__builtin_bit_cast(uint32_t, kmax[r]) & 1023u);
    }
    asm volatile("s_waitcnt lgkmcnt(0)" ::: "memory");

    // gather fp32 codebook rows + write out + e2 loss term
#pragma unroll
    for (int it = 0; it < 4; ++it) {
      int rloc = it * 4 + lg;
      int idx = sh_idx[rloc];
      f32x4 q = *(const f32x4*)(cb + (size_t)idx * 64 + lr * 4);
      __builtin_nontemporal_store(
          q, (f32x4*)(out + (size_t)(rowbase + pass * 16 + rloc) * 64 + lr * 4));
      if (lr == 0) lsum += e2f[idx];
    }
  }

  // ---- loss reduction: wave -> block -> global atomic ----
#pragma unroll
  for (int m = 1; m < 64; m <<= 1) lsum += __shfl_xor(lsum, m, 64);
  float* shl = (float*)(smem + SM_LOSS);
  if (lane == 0) shl[w] = lsum;
  __syncthreads();
  if (tid == 0) {
    float s = 0.f;
#pragma unroll
    for (int i = 0; i < 8; ++i) s += shl[i];
    atomicAdd(loss, s * (1.25f / 8388608.0f));
  }
}

extern "C" void kernel_launch(void* const* d_in, const int* in_sizes, int n_in,
                              void* d_out, int out_size, void* d_ws, size_t ws_size,
                              hipStream_t stream) {
  const float* x  = (const float*)d_in[0];
  const float* cb = (const float*)d_in[1];
  float* out = (float*)d_out;
  uint8_t* ws = (uint8_t*)d_ws;
  float* loss = out + 8388608;

  hipMemsetAsync(loss, 0, 4, stream);
  hipLaunchKernelGGL(prep_kernel, dim3(8), dim3(512), 0, stream, cb, ws);
  hipLaunchKernelGGL(vq_main, dim3(512), dim3(512), 0, stream, x, cb, out, ws, loss);
}

// Round 4
// 32.045 us; speedup vs baseline: 1.0332x; 1.0332x over previous
//
#include <hip/hip_runtime.h>
#include <stdint.h>

typedef float    f32x4 __attribute__((ext_vector_type(4)));
typedef uint32_t u32x4 __attribute__((ext_vector_type(4)));

// ws layout (bytes):
//  [0, 65536)       fp8 codebook, t-grouped lane order:
//                   chunk c = t*64 + l (t=code tile, l=lane): 16B at c*16 =
//                   { fp8(1024*e[16t+(l&15)][(l>>4)*8 .. +8)),
//                     fp8(1024*e[16t+(l&15)][32+(l>>4)*8 .. +8)) }
//  [65536, 69632)   e2 fp32[1024] (unscaled, exact)
#define WS_E2   65536

// LDS: mirrors ws [0,69632) linearly, + idx + loss scratch
#define SM_E2   65536
#define SM_IDX  69632   // 4 waves * 32 int = 512B
#define SM_LOSS 70144   // 4 floats
#define SM_SZ   70160

__device__ __forceinline__ uint32_t pk4(float a, float b, float c, float d) {
  int v = 0;
  v = __builtin_amdgcn_cvt_pk_fp8_f32(a, b, v, false);
  v = __builtin_amdgcn_cvt_pk_fp8_f32(c, d, v, true);
  return (uint32_t)v;
}

__device__ __forceinline__ float d4(f32x4 v) {
  return v[0]*v[0] + v[1]*v[1] + v[2]*v[2] + v[3]*v[3];
}

// 8 blocks x 512: thread -> one 16B fp8 chunk + one e2 quarter-row (coalesced).
// Also zeroes the loss slot (replaces a memset dispatch).
__global__ __launch_bounds__(512) void prep_kernel(const float* __restrict__ cb,
                                                   uint8_t* __restrict__ ws,
                                                   float* __restrict__ loss) {
  const int tid = threadIdx.x;
  if (blockIdx.x == 0 && tid == 0) *loss = 0.f;
  const int c = blockIdx.x * 512 + tid;          // 0..4095
  const int t = c >> 6, l = c & 63, lr = l & 15, lg = l >> 4;
  {
    const float* row = cb + (size_t)(t * 16 + lr) * 64 + lg * 8;
    f32x4 a0 = *(const f32x4*)row;
    f32x4 a1 = *(const f32x4*)(row + 4);
    f32x4 b0 = *(const f32x4*)(row + 32);
    f32x4 b1 = *(const f32x4*)(row + 36);
    u32x4 o;
    o[0] = pk4(1024.f*a0[0], 1024.f*a0[1], 1024.f*a0[2], 1024.f*a0[3]);
    o[1] = pk4(1024.f*a1[0], 1024.f*a1[1], 1024.f*a1[2], 1024.f*a1[3]);
    o[2] = pk4(1024.f*b0[0], 1024.f*b0[1], 1024.f*b0[2], 1024.f*b0[3]);
    o[3] = pk4(1024.f*b1[0], 1024.f*b1[1], 1024.f*b1[2], 1024.f*b1[3]);
    *(u32x4*)(ws + (size_t)c * 16) = o;
  }
  {
    const int r = blockIdx.x * 128 + (tid >> 2), q = tid & 3;
    const float* rp = cb + (size_t)r * 64 + q * 16;
    f32x4 v0 = *(const f32x4*)rp;
    f32x4 v1 = *(const f32x4*)(rp + 4);
    f32x4 v2 = *(const f32x4*)(rp + 8);
    f32x4 v3 = *(const f32x4*)(rp + 12);
    float s = d4(v0) + d4(v1) + d4(v2) + d4(v3);
    s += __shfl_xor(s, 1, 64);
    s += __shfl_xor(s, 2, 64);
    if (q == 0) *(float*)(ws + WS_E2 + (size_t)r * 4) = s;
  }
}

// single scan over all 64 code-tiles: B read ONCE per tile, both row-tiles' MFMAs share it
__device__ __forceinline__ void scan64(const uint8_t* __restrict__ smem, int lane, int lr,
                                       const long a[2][2], float kmax[2][4]) {
#pragma unroll
  for (int rt = 0; rt < 2; ++rt)
#pragma unroll
    for (int r = 0; r < 4; ++r) kmax[rt][r] = __builtin_bit_cast(float, 0xFF800000u);
  const uint8_t* bptr = smem + lane * 16;
  uint32_t jcur = (uint32_t)lr;
#pragma unroll 4
  for (int t = 0; t < 64; ++t) {
    u32x4 b = *(const u32x4*)(bptr + t * 1024);
    long bf0 = (long)(((uint64_t)b[1] << 32) | b[0]);
    long bf1 = (long)(((uint64_t)b[3] << 32) | b[2]);
#pragma unroll
    for (int rt = 0; rt < 2; ++rt) {
      f32x4 acc = {0.f, 0.f, 0.f, 0.f};
      acc = __builtin_amdgcn_mfma_f32_16x16x32_fp8_fp8(a[rt][0], bf0, acc, 0, 0, 0);
      acc = __builtin_amdgcn_mfma_f32_16x16x32_fp8_fp8(a[rt][1], bf1, acc, 0, 0, 0);
#pragma unroll
      for (int r = 0; r < 4; ++r) {
        uint32_t key = (__builtin_bit_cast(uint32_t, acc[r]) & 0xFFFFFC00u) | jcur;
        kmax[rt][r] = fmaxf(kmax[rt][r], __builtin_bit_cast(float, key));
      }
    }
    jcur += 16;
  }
}

// reduce -> idx exchange -> gather/store 32 rows; returns loss contribution
__device__ __forceinline__ float finish32(uint8_t* __restrict__ smem, float kmax[2][4],
                                          const float* __restrict__ cb,
                                          float* __restrict__ out,
                                          int rowbase, int w, int lr, int lg) {
  float ls = 0.f;
#pragma unroll
  for (int rt = 0; rt < 2; ++rt)
#pragma unroll
    for (int r = 0; r < 4; ++r) {
      float v = kmax[rt][r];
#pragma unroll
      for (int m = 1; m < 16; m <<= 1) v = fmaxf(v, __shfl_xor(v, m, 64));
      kmax[rt][r] = v;
      ls -= __builtin_bit_cast(float, __builtin_bit_cast(uint32_t, v) & 0xFFFFFC00u)
            * (1.0f / 8192.0f);
    }
  int* sh_idx = (int*)(smem + SM_IDX) + w * 32;
  if (lr == 0) {
#pragma unroll
    for (int rt = 0; rt < 2; ++rt)
#pragma unroll
      for (int r = 0; r < 4; ++r)
        sh_idx[rt * 16 + lg * 4 + r] =
            (int)(__builtin_bit_cast(uint32_t, kmax[rt][r]) & 1023u);
  }
  asm volatile("s_waitcnt lgkmcnt(0)" ::: "memory");
  const float* e2f = (const float*)(smem + SM_E2);
#pragma unroll
  for (int it = 0; it < 8; ++it) {
    int rloc = it * 4 + lg;
    int idx = sh_idx[rloc];
    f32x4 q = *(const f32x4*)(cb + (size_t)idx * 64 + lr * 4);
    __builtin_nontemporal_store(q, (f32x4*)(out + (size_t)(rowbase + rloc) * 64 + lr * 4));
    if (lr == 0) ls += e2f[idx];
  }
  return ls;
}

__device__ __forceinline__ void loadx(const float* __restrict__ x, int rowbase,
                                      int lr, int lg, f32x4 r[2][4]) {
#pragma unroll
  for (int rt = 0; rt < 2; ++rt) {
    const float* rp = x + (size_t)(rowbase + rt * 16 + lr) * 64 + lg * 8;
    r[rt][0] = __builtin_nontemporal_load((const f32x4*)rp);
    r[rt][1] = __builtin_nontemporal_load((const f32x4*)(rp + 4));
    r[rt][2] = __builtin_nontemporal_load((const f32x4*)(rp + 32));
    r[rt][3] = __builtin_nontemporal_load((const f32x4*)(rp + 36));
  }
}

__device__ __forceinline__ void packA(const f32x4 r[2][4], long a[2][2], float& x2) {
#pragma unroll
  for (int rt = 0; rt < 2; ++rt) {
    x2 += d4(r[rt][0]) + d4(r[rt][1]) + d4(r[rt][2]) + d4(r[rt][3]);
    uint32_t w0 = pk4(r[rt][0][0], r[rt][0][1], r[rt][0][2], r[rt][0][3]);
    uint32_t w1 = pk4(r[rt][1][0], r[rt][1][1], r[rt][1][2], r[rt][1][3]);
    uint32_t w2 = pk4(r[rt][2][0], r[rt][2][1], r[rt][2][2], r[rt][2][3]);
    uint32_t w3 = pk4(r[rt][3][0], r[rt][3][1], r[rt][3][2], r[rt][3][3]);
    a[rt][0] = (long)(((uint64_t)w1 << 32) | w0);
    a[rt][1] = (long)(((uint64_t)w3 << 32) | w2);
  }
}

// 512 blocks x 256 threads (2 blocks/CU); each block: 2 chunks of 128 rows,
// chunk1 x-loads stream under chunk0's scan; chunk0 stores drain under chunk1's scan.
__global__ __launch_bounds__(256, 2) void vq_main(const float* __restrict__ x,
                                                  const float* __restrict__ cb,
                                                  float* __restrict__ out,
                                                  const uint8_t* __restrict__ ws,
                                                  float* __restrict__ loss) {
  __shared__ __align__(16) uint8_t smem[SM_SZ];
  const int tid = threadIdx.x, lane = tid & 63, w = tid >> 6;
  const int lr = lane & 15, lg = lane >> 4;
  const int rowbase0 = blockIdx.x * 256 + w * 32;
  const int rowbase1 = rowbase0 + 128;

  // issue async staging: fp8 codebook (64KB) + e2 (4KB), linear copy
  for (int off = tid * 16; off < 69632; off += 4096)
    __builtin_amdgcn_global_load_lds(
        (const __attribute__((address_space(1))) uint32_t*)(ws + off),
        (__attribute__((address_space(3))) uint32_t*)(smem + off), 16, 0, 0);

  // chunk0: load + pack (overlaps staging)
  f32x4 r0[2][4];
  loadx(x, rowbase0, lr, lg, r0);
  float lsum = 0.f;
  long a0[2][2];
  packA(r0, a0, lsum);
  __syncthreads();   // staging (and chunk0) complete

  // prefetch chunk1 AFTER the barrier: streams under scan0
  f32x4 r1[2][4];
  loadx(x, rowbase1, lr, lg, r1);

  float kmax[2][4];
  scan64(smem, lane, lr, a0, kmax);
  lsum += finish32(smem, kmax, cb, out, rowbase0, w, lr, lg);

  long a1[2][2];
  packA(r1, a1, lsum);
  scan64(smem, lane, lr, a1, kmax);
  lsum += finish32(smem, kmax, cb, out, rowbase1, w, lr, lg);

  // loss: wave -> block -> global atomic (loss zeroed by prep)
#pragma unroll
  for (int m = 1; m < 64; m <<= 1) lsum += __shfl_xor(lsum, m, 64);
  float* shl = (float*)(smem + SM_LOSS);
  if (lane == 0) shl[w] = lsum;
  __syncthreads();
  if (tid == 0) {
    float s = shl[0] + shl[1] + shl[2] + shl[3];
    atomicAdd(loss, s * (1.25f / 8388608.0f));
  }
}

extern "C" void kernel_launch(void* const* d_in, const int* in_sizes, int n_in,
                              void* d_out, int out_size, void* d_ws, size_t ws_size,
                              hipStream_t stream) {
  const float* x  = (const float*)d_in[0];
  const float* cb = (const float*)d_in[1];
  float* out = (float*)d_out;
  uint8_t* ws = (uint8_t*)d_ws;
  float* loss = out + 8388608;

  hipLaunchKernelGGL(prep_kernel, dim3(8), dim3(512), 0, stream, cb, ws, loss);
  hipLaunchKernelGGL(vq_main, dim3(512), dim3(256), 0, stream, x, cb, out, ws, loss);
}